// Round 24
// baseline (285.715 us; speedup 1.0000x reference)
//
#include <hip/hip_runtime.h>
#include <hip/hip_bf16.h>

typedef __attribute__((ext_vector_type(4))) float f32x4;
typedef __attribute__((ext_vector_type(4))) int   int4v;
typedef __attribute__((ext_vector_type(2))) int   int2v;
typedef __attribute__((ext_vector_type(16))) int  i32x16;

#define N_NBR 65536
#define INIT_DIM 512
#define HID 1024
#define NTILE 3072
#define NBLOCK 512
#define TPB 6
#define SA 24.0f
#define SW 1024.0f
#define INVS (1.0f / (24.0f * 1024.0f))

static __device__ __forceinline__ int q8(float x, float s) {
  float y = fminf(fmaxf(x * s, -127.f), 127.f);
  return __float2int_rn(y);
}
static __device__ __forceinline__ int pack4(float a, float b, float c, float d, float s) {
  return (q8(a,s) & 255) | ((q8(b,s) & 255) << 8) | ((q8(c,s) & 255) << 16) | ((q8(d,s) & 255) << 24);
}

// Relayout W (3x [1024 n][512 k] f32) -> i8 fragments for mfma_i32_32x32x32_i8.
__global__ __launch_bounds__(256) void k_convw(const float* __restrict__ wa,
                                               const float* __restrict__ wb,
                                               const float* __restrict__ wc,
                                               char* __restrict__ out) {
  int g = blockIdx.x * 256 + threadIdx.x;   // 0..98303
  int l = g & 63;
  int blk = g >> 6;           // t*512 + nb*16 + ks
  int ks = blk & 15;
  int nb = (blk >> 4) & 31;
  int t = blk >> 9;
  const float* src = (t == 0) ? wa : (t == 1) ? wb : wc;
  int n = nb * 32 + (l & 31);
  int k0 = ks * 32 + (l >> 5) * 16;
  const f32x4* p = (const f32x4*)(src + (size_t)n * INIT_DIM + k0);
  f32x4 x0 = p[0], x1 = p[1], x2 = p[2], x3 = p[3];
  int4v v;
  v[0] = pack4(x0.x, x0.y, x0.z, x0.w, SW);
  v[1] = pack4(x1.x, x1.y, x1.z, x1.w, SW);
  v[2] = pack4(x2.x, x2.y, x2.z, x2.w, SW);
  v[3] = pack4(x3.x, x3.y, x3.z, x3.w, SW);
  *(int4v*)(out + (size_t)g * 16) = v;
}

// Main: PRODUCER/CONSUMER wave specialization (dispatch-order-safe: all
// sync is __syncthreads within a block). 512 blocks x 256 thr, 6 tiles each,
// LDS 2x32KB ping-pong. Waves 0-1 = producers: gather+quant+swizzled-write
// tile q+1 into buf[(q+1)&1] (32 rows each). Waves 2-3 = consumers: R17's
// proven i8 K-loop (mf=2 nf=2, 64 AGPR) on buf[q&1], 512 cols each
// (8 passes). ONE barrier per tile. Gather latency runs continuously on
// producer waves while consumer waves feed the matrix pipe — the regime
// separation R22 measured as floors (gather 123us | GEMM 124us) without
// paying the split's serialization.
__global__ __launch_bounds__(256) void k_main(
    const float* __restrict__ fa, const float* __restrict__ fb, const float* __restrict__ fc,
    const int* __restrict__ na, const int* __restrict__ nb_, const int* __restrict__ nc__,
    const float* __restrict__ b1a, const float* __restrict__ b1b, const float* __restrict__ b1c,
    const char* __restrict__ wbf8,            // [3][32 nb][16 ks][1024B] i8 fragments
    float* __restrict__ partials) {           // [NTILE][HID]
  __shared__ __align__(16) char Asm[2][64 * 512];   // 2 x 32 KB

  int bx = blockIdx.x;
  int tid = threadIdx.x;
  int wave = tid >> 6;          // 0..3
  int lane = tid & 63;
  int l31 = lane & 31, hi = lane >> 5;

  auto featsel = [&](int t) { return (t == 0) ? fa : (t == 1) ? fb : fc; };
  auto nbrsel  = [&](int t) { return (t == 0) ? na : (t == 1) ? nb_ : nc__; };
  auto biassel = [&](int t) { return (t == 0) ? b1a : (t == 1) ? b1b : b1c; };

  int tile0 = bx * TPB;

  // ---- prologue: ALL 4 waves stage tile0 into Asm[0] (rows c*4+wave).
  {
    int t0 = tile0 >> 10, mt0 = tile0 & 1023;
    const int* nbr0 = nbrsel(t0);
    const float* feat0 = featsel(t0);
    #pragma unroll 2
    for (int c = 0; c < 16; ++c) {
      int r = c * 4 + wave;
      int idx = nbr0[mt0 * 64 + r];
      const float* rp = feat0 + (size_t)idx * INIT_DIM + lane * 8;
      f32x4 a  = *(const f32x4*)rp;
      f32x4 b2 = *((const f32x4*)rp + 1);
      int2v v;
      v[0] = pack4(a.x, a.y, a.z, a.w, SA);
      v[1] = pack4(b2.x, b2.y, b2.z, b2.w, SA);
      unsigned byte = (unsigned)r * 512u +
                      (((unsigned)lane * 8u) ^ ((unsigned)(r & 31) << 4));
      *(int2v*)(&Asm[0][0] + byte) = v;
    }
  }
  __syncthreads();

  // A-read swizzle (consumers): byte = r*512 + ((ks*32+hi*16) ^ ((r&31)<<4)).
  unsigned swz = (unsigned)l31 << 4;
  unsigned abase = (unsigned)l31 * 512u + (((unsigned)hi << 4) ^ (swz & 16u));
  unsigned swzhi = swz & 0x1E0u;

  for (int q = 0; q < TPB; ++q) {
    int tile_id = tile0 + q;
    int t = tile_id >> 10;

    if (wave < 2) {
      // ---- PRODUCER: stage tile q+1 into the other buffer (32 rows/wave).
      if (q + 1 < TPB) {
        int tn = tile_id + 1;
        int tt = tn >> 10, mtn = tn & 1023;
        const int* nbrn = nbrsel(tt);
        const float* featn = featsel(tt);
        char* wbuf = &Asm[(q + 1) & 1][0];
        #pragma unroll 4
        for (int c = 0; c < 32; ++c) {
          int r = c * 2 + wave;
          int idx = nbrn[mtn * 64 + r];
          const float* rp = featn + (size_t)idx * INIT_DIM + lane * 8;
          f32x4 a  = *(const f32x4*)rp;
          f32x4 b2 = *((const f32x4*)rp + 1);
          int2v v;
          v[0] = pack4(a.x, a.y, a.z, a.w, SA);
          v[1] = pack4(b2.x, b2.y, b2.z, b2.w, SA);
          unsigned byte = (unsigned)r * 512u +
                          (((unsigned)lane * 8u) ^ ((unsigned)(r & 31) << 4));
          *(int2v*)(wbuf + byte) = v;
        }
      }
    } else {
      // ---- CONSUMER: R17 K-loop on buf[q&1]; wave cw covers 512 cols.
      int cw = wave - 2;
      const char* rbuf = &Asm[q & 1][0];
      const char* Wf8 = wbf8 + (size_t)t * (32 * 16 * 1024);
      const float* bias = biassel(t);
      #pragma unroll 2
      for (int p = 0; p < 8; ++p) {
        const char* pBa = Wf8 + ((size_t)(cw * 16 + p * 2)     << 14) + lane * 16;
        const char* pBb = Wf8 + ((size_t)(cw * 16 + p * 2 + 1) << 14) + lane * 16;
        i32x16 acc[2][2] = {};   // [mf][nf] -> 64 AGPR
        #pragma unroll 4
        for (int ks = 0; ks < 16; ++ks) {
          int4v Bf0 = *(const int4v*)(pBa + (ks << 10));
          int4v Bf1 = *(const int4v*)(pBb + (ks << 10));
          unsigned kcol = (((unsigned)ks << 5) ^ swzhi);
          int4v Af[2];
          #pragma unroll
          for (int i = 0; i < 2; ++i)
            Af[i] = *(const int4v*)(rbuf + (abase + (unsigned)(i * 16384) + kcol));
          #pragma unroll
          for (int i = 0; i < 2; ++i) {
            acc[i][0] = __builtin_amdgcn_mfma_i32_32x32x32_i8(Af[i], Bf0, acc[i][0], 0, 0, 0);
            acc[i][1] = __builtin_amdgcn_mfma_i32_32x32x32_i8(Af[i], Bf1, acc[i][1], 0, 0, 0);
          }
        }
        // Integer epilogue: relu(acc*INVS + b) = INVS * max(acc + bq, 0).
        #pragma unroll
        for (int j = 0; j < 2; ++j) {
          int n = (cw * 16 + p * 2 + j) * 32 + l31;
          int bq = __float2int_rn(bias[n] * (SA * SW));
          int s = 0;
          #pragma unroll
          for (int i = 0; i < 2; ++i)
            #pragma unroll
            for (int r = 0; r < 16; ++r)
              s += max(acc[i][j][r] + bq, 0);
          s += __shfl_xor(s, 32);
          if (hi == 0) partials[(size_t)tile_id * HID + n] = (float)s * INVS;
        }
      }
    }
    __syncthreads();
  }
}

// Reduce stage 1: coalesced f32x4 sums of 16-row slabs -> inter[192][1024].
__global__ __launch_bounds__(256) void k_reduce1(const float* __restrict__ partials,
                                                 float* __restrict__ inter) {
  int b = blockIdx.x;
  int tid = threadIdx.x;
  const f32x4* base = (const f32x4*)(partials + (size_t)b * 16 * HID) + tid;
  f32x4 s = {0.f, 0.f, 0.f, 0.f};
  #pragma unroll 4
  for (int r = 0; r < 16; ++r) {
    f32x4 v = base[r * (HID / 4)];
    s.x += v.x; s.y += v.y; s.z += v.z; s.w += v.w;
  }
  *((f32x4*)(inter + (size_t)b * HID) + tid) = s;
}

// Reduce stage 2: one 1024-thread block, col per thread.
__global__ __launch_bounds__(1024) void k_reduce2(const float* __restrict__ inter,
                                                  float* __restrict__ acc) {
  int col = threadIdx.x;
  float s = 0.f;
  #pragma unroll 8
  for (int r = 0; r < 192; ++r) s += inter[(size_t)r * HID + col];
  acc[col] = s;
}

// pooled = acc/196608 ; feat_all = relu ; logits = feat_all @ Wc.T + bc
__global__ __launch_bounds__(256) void k_final(const float* __restrict__ acc,
                                               const float* __restrict__ Wc,
                                               const float* __restrict__ bc,
                                               float* __restrict__ out) {
  __shared__ float fall[HID];
  int tid = threadIdx.x;
  const float inv = 1.f / (3.f * (float)N_NBR);
  for (int i = tid; i < HID; i += 256) {
    float p = acc[i] * inv;
    fall[i] = (p > 0.f) ? p : 0.f;
  }
  __syncthreads();
  int o = tid >> 2, q = tid & 3;
  const f32x4* w = (const f32x4*)(Wc + (size_t)o * HID + q * 256);
  const f32x4* f = (const f32x4*)(fall + q * 256);
  float s = 0.f;
  #pragma unroll 4
  for (int k = 0; k < 64; ++k) {
    f32x4 wv = w[k], fv = f[k];
    s += wv.x * fv.x + wv.y * fv.y + wv.z * fv.z + wv.w * fv.w;
  }
  s += __shfl_xor(s, 1);
  s += __shfl_xor(s, 2);
  if (q == 0) out[o] = s + bc[o];
}

extern "C" void kernel_launch(void* const* d_in, const int* in_sizes, int n_in,
                              void* d_out, int out_size, void* d_ws, size_t ws_size,
                              hipStream_t stream) {
  const float* fa  = (const float*)d_in[1];
  const int*   na  = (const int*)d_in[2];
  const float* W1a = (const float*)d_in[3];
  const float* b1a = (const float*)d_in[4];
  const float* fb  = (const float*)d_in[5];
  const int*   nb  = (const int*)d_in[6];
  const float* W1b = (const float*)d_in[7];
  const float* b1b = (const float*)d_in[8];
  const float* fc  = (const float*)d_in[9];
  const int*   nc  = (const int*)d_in[10];
  const float* W1c = (const float*)d_in[11];
  const float* b1c = (const float*)d_in[12];
  const float* Wc  = (const float*)d_in[13];
  const float* bc  = (const float*)d_in[14];
  float* out = (float*)d_out;

  float* acc = (float*)d_ws;                                       // 1024 f32
  char*  wbf8 = (char*)d_ws + 4096;                                // 1.5 MB i8 fragments
  float* partials = (float*)((char*)d_ws + 4096 + 3 * 32 * 16 * 1024);        // 12.6 MB
  float* inter = partials + (size_t)NTILE * HID;                   // 768 KB

  k_convw<<<384, 256, 0, stream>>>(W1a, W1b, W1c, wbf8);
  k_main<<<NBLOCK, 256, 0, stream>>>(fa, fb, fc, na, nb, nc, b1a, b1b, b1c, wbf8, partials);
  k_reduce1<<<192, 256, 0, stream>>>(partials, inter);
  k_reduce2<<<1, 1024, 0, stream>>>(inter, acc);
  k_final<<<1, 256, 0, stream>>>(acc, Wc, bc, out);
}

// Round 25
// 177.074 us; speedup vs baseline: 1.6135x; 1.6135x over previous
//
#include <hip/hip_runtime.h>
#include <hip/hip_bf16.h>

typedef __attribute__((ext_vector_type(4))) float f32x4;
typedef __attribute__((ext_vector_type(4))) int   int4v;
typedef __attribute__((ext_vector_type(2))) int   int2v;
typedef __attribute__((ext_vector_type(16))) int  i32x16;

#define N_NBR 65536
#define INIT_DIM 512
#define HID 1024
#define NTILE 3072     // 3 types x 1024 tiles (64 rows each)
#define NBLOCK 512     // 2 blocks/CU
#define TPB 6          // tiles per block
#define SA 24.0f
#define SW 1024.0f
#define INVS (1.0f / (24.0f * 1024.0f))

static __device__ __forceinline__ int q8(float x, float s) {
  float y = fminf(fmaxf(x * s, -127.f), 127.f);
  return __float2int_rn(y);
}
static __device__ __forceinline__ int pack4(float a, float b, float c, float d, float s) {
  return (q8(a,s) & 255) | ((q8(b,s) & 255) << 8) | ((q8(c,s) & 255) << 16) | ((q8(d,s) & 255) << 24);
}

// Relayout W (3x [1024 n][512 k] f32) -> i8 fragments for mfma_i32_32x32x32_i8:
// block (t, nb 0..31, ks 0..15): 1KB contiguous; lane l holds
// W[nb*32 + (l&31)][ks*32 + (l>>5)*16 + j], j=0..15 (16 bytes).
__global__ __launch_bounds__(256) void k_convw(const float* __restrict__ wa,
                                               const float* __restrict__ wb,
                                               const float* __restrict__ wc,
                                               char* __restrict__ out) {
  int g = blockIdx.x * 256 + threadIdx.x;   // 0..98303
  int l = g & 63;
  int blk = g >> 6;           // t*512 + nb*16 + ks
  int ks = blk & 15;
  int nb = (blk >> 4) & 31;
  int t = blk >> 9;
  const float* src = (t == 0) ? wa : (t == 1) ? wb : wc;
  int n = nb * 32 + (l & 31);
  int k0 = ks * 32 + (l >> 5) * 16;
  const f32x4* p = (const f32x4*)(src + (size_t)n * INIT_DIM + k0);
  f32x4 x0 = p[0], x1 = p[1], x2 = p[2], x3 = p[3];
  int4v v;
  v[0] = pack4(x0.x, x0.y, x0.z, x0.w, SW);
  v[1] = pack4(x1.x, x1.y, x1.z, x1.w, SW);
  v[2] = pack4(x2.x, x2.y, x2.z, x2.w, SW);
  v[3] = pack4(x3.x, x3.y, x3.z, x3.w, SW);
  *(int4v*)(out + (size_t)g * 16) = v;
}

// Main (R20, session best 178.7us): R17's i8 tile shape (mf=2 nf=2, 64 AGPR,
// 0-conflict swizzle) inside the prefetch structure: 512 blocks x 256 thr
// (2 blocks/CU, LDS 2x32KB dbuf), 6 tiles each. Gather-group p of the NEXT
// tile is issued before pass p and quant+written after pass p into the other
// LDS buffer. ONE barrier per tile. 24-round ledger: all structural variants
// (occupancy 22-44%, pipe rebalance, rings, phase-split, dedup, split,
// producer/consumer) land >=176us or regress; floors are gather=123 /
// GEMM=124 (R22 split) -> this is ~79% of perfect-overlap ideal.
__global__ __launch_bounds__(256) void k_main(
    const float* __restrict__ fa, const float* __restrict__ fb, const float* __restrict__ fc,
    const int* __restrict__ na, const int* __restrict__ nb_, const int* __restrict__ nc__,
    const float* __restrict__ b1a, const float* __restrict__ b1b, const float* __restrict__ b1c,
    const char* __restrict__ wbf8,            // [3][32 nb][16 ks][1024B] i8 fragments
    float* __restrict__ partials) {           // [NTILE][HID]
  __shared__ __align__(16) char Asm[2][64 * 512];   // 2 x 32 KB

  int bx = blockIdx.x;
  int tid = threadIdx.x;
  int wave = tid >> 6;          // 0..3
  int lane = tid & 63;
  int l31 = lane & 31, hi = lane >> 5;

  auto featsel = [&](int t) { return (t == 0) ? fa : (t == 1) ? fb : fc; };
  auto nbrsel  = [&](int t) { return (t == 0) ? na : (t == 1) ? nb_ : nc__; };
  auto biassel = [&](int t) { return (t == 0) ? b1a : (t == 1) ? b1b : b1c; };

  // A-read swizzle (512B rows): byte = r*512 + ((ks*32+hi*16)^((r&31)<<4));
  // r = i*32+l31 -> (r&31)==l31. Disjoint bits: bit4 in abase, bits>=5 per-ks.
  unsigned swz = (unsigned)l31 << 4;
  unsigned abase = (unsigned)l31 * 512u + (((unsigned)hi << 4) ^ (swz & 16u));
  unsigned swzhi = swz & 0x1E0u;

  int tile0 = bx * TPB;
  int idxr[16];    // next tile's row indices: row (c*4 + wave) for c=0..15
  f32x4 hold[4][2];

  // ---- prologue: stage tile0 into Asm[0]; then preload idxr for tile1.
  {
    int t0 = tile0 >> 10, mt0 = tile0 & 1023;
    const int* nbr0 = nbrsel(t0);
    const float* feat0 = featsel(t0);
    #pragma unroll 2
    for (int c = 0; c < 16; ++c) {
      int r = c * 4 + wave;
      int idx = nbr0[mt0 * 64 + r];
      const float* rp = feat0 + (size_t)idx * INIT_DIM + lane * 8;
      f32x4 a  = *(const f32x4*)rp;
      f32x4 b2 = *((const f32x4*)rp + 1);
      int2v v;
      v[0] = pack4(a.x, a.y, a.z, a.w, SA);
      v[1] = pack4(b2.x, b2.y, b2.z, b2.w, SA);
      unsigned byte = (unsigned)r * 512u +
                      (((unsigned)lane * 8u) ^ ((unsigned)(r & 31) << 4));
      *(int2v*)(&Asm[0][0] + byte) = v;
    }
    int tn = tile0 + 1;
    const int* nbr1 = nbrsel(tn >> 10);
    int mt1 = tn & 1023;
    #pragma unroll
    for (int c = 0; c < 16; ++c) idxr[c] = nbr1[mt1 * 64 + c * 4 + wave];
  }
  __syncthreads();

  for (int q = 0; q < TPB; ++q) {
    int tile_id = tile0 + q;
    int t = tile_id >> 10;
    const char* Wf8 = wbf8 + (size_t)t * (32 * 16 * 1024);
    const float* bias = biassel(t);
    const char* rbuf = &Asm[q & 1][0];
    char* wbuf = &Asm[(q + 1) & 1][0];
    bool pf = (q + 1 < TPB);
    const float* featn = pf ? featsel((tile_id + 1) >> 10) : fa;

    #pragma unroll
    for (int p = 0; p < 4; ++p) {
      // 1) issue gather group p for next tile (4 rows/wave, in-flight regs)
      if (pf) {
        #pragma unroll
        for (int k = 0; k < 4; ++k) {
          int idx = idxr[p * 4 + k];
          const float* rp = featn + (size_t)idx * INIT_DIM + lane * 8;
          hold[k][0] = *(const f32x4*)rp;
          hold[k][1] = *((const f32x4*)rp + 1);
        }
      }
      // 2) PASS p: i8 K-loop. B: nb = wave*8 + p*2 + j.
      const char* pBa = Wf8 + ((size_t)(wave * 8 + p * 2)     << 14) + lane * 16;
      const char* pBb = Wf8 + ((size_t)(wave * 8 + p * 2 + 1) << 14) + lane * 16;
      i32x16 acc[2] = {};
      i32x16 acd[2] = {};
      #pragma unroll 4
      for (int ks = 0; ks < 16; ++ks) {
        int4v Bf0 = *(const int4v*)(pBa + (ks << 10));
        int4v Bf1 = *(const int4v*)(pBb + (ks << 10));
        unsigned kcol = (((unsigned)ks << 5) ^ swzhi);
        int4v Af0 = *(const int4v*)(rbuf + (abase + kcol));
        int4v Af1 = *(const int4v*)(rbuf + (abase + 16384u + kcol));
        acc[0] = __builtin_amdgcn_mfma_i32_32x32x32_i8(Af0, Bf0, acc[0], 0, 0, 0);
        acc[1] = __builtin_amdgcn_mfma_i32_32x32x32_i8(Af0, Bf1, acc[1], 0, 0, 0);
        acd[0] = __builtin_amdgcn_mfma_i32_32x32x32_i8(Af1, Bf0, acd[0], 0, 0, 0);
        acd[1] = __builtin_amdgcn_mfma_i32_32x32x32_i8(Af1, Bf1, acd[1], 0, 0, 0);
      }
      // integer epilogue: relu(acc*INVS+b) = INVS*max(acc+bq,0)
      #pragma unroll
      for (int j = 0; j < 2; ++j) {
        int n = (wave * 8 + p * 2 + j) * 32 + l31;
        int bq = __float2int_rn(bias[n] * (SA * SW));
        int s = 0;
        #pragma unroll
        for (int r = 0; r < 16; ++r) s += max(acc[j][r] + bq, 0);
        #pragma unroll
        for (int r = 0; r < 16; ++r) s += max(acd[j][r] + bq, 0);
        s += __shfl_xor(s, 32);
        if (hi == 0) partials[(size_t)tile_id * HID + n] = (float)s * INVS;
      }
      // 3) quant + write group p into the other buffer (loads have landed)
      if (pf) {
        #pragma unroll
        for (int k = 0; k < 4; ++k) {
          int r = (p * 4 + k) * 4 + wave;
          f32x4 a = hold[k][0], b2 = hold[k][1];
          int2v v;
          v[0] = pack4(a.x, a.y, a.z, a.w, SA);
          v[1] = pack4(b2.x, b2.y, b2.z, b2.w, SA);
          unsigned byte = (unsigned)r * 512u +
                          (((unsigned)lane * 8u) ^ ((unsigned)(r & 31) << 4));
          *(int2v*)(wbuf + byte) = v;
        }
      }
    }
    // preload idxr for tile q+2
    if (pf && q + 2 < TPB) {
      int tn2 = tile_id + 2;
      const int* nbrn = nbrsel(tn2 >> 10);
      int mtn = tn2 & 1023;
      #pragma unroll
      for (int c = 0; c < 16; ++c) idxr[c] = nbrn[mtn * 64 + c * 4 + wave];
    }
    __syncthreads();
  }
}

// Reduce stage 1: 192 blocks; block b sums partials rows [b*16, b*16+16)
// over all 1024 cols with coalesced f32x4 reads -> inter[b][1024].
__global__ __launch_bounds__(256) void k_reduce1(const float* __restrict__ partials,
                                                 float* __restrict__ inter) {
  int b = blockIdx.x;          // 0..191
  int tid = threadIdx.x;       // f32x4 column group
  const f32x4* base = (const f32x4*)(partials + (size_t)b * 16 * HID) + tid;
  f32x4 s = {0.f, 0.f, 0.f, 0.f};
  #pragma unroll 4
  for (int r = 0; r < 16; ++r) {
    f32x4 v = base[r * (HID / 4)];
    s.x += v.x; s.y += v.y; s.z += v.z; s.w += v.w;
  }
  *((f32x4*)(inter + (size_t)b * HID) + tid) = s;
}

// Merged reduce2+final: 1 block x 1024 thr.
// Phase 1: col-per-thread sum of inter[192][1024] -> fall (relu'd, scaled).
// Phase 2: first 256 threads compute logits = fall @ Wc.T + bc.
__global__ __launch_bounds__(1024) void k_reduce2_final(const float* __restrict__ inter,
                                                        const float* __restrict__ Wc,
                                                        const float* __restrict__ bc,
                                                        float* __restrict__ out) {
  __shared__ float fall[HID];
  int col = threadIdx.x;
  const float inv = 1.f / (3.f * (float)N_NBR);
  float s = 0.f;
  #pragma unroll 8
  for (int r = 0; r < 192; ++r) s += inter[(size_t)r * HID + col];
  float p = s * inv;
  fall[col] = (p > 0.f) ? p : 0.f;
  __syncthreads();
  if (col < 256) {
    int o = col >> 2, q = col & 3;
    const f32x4* w = (const f32x4*)(Wc + (size_t)o * HID + q * 256);
    const f32x4* f = (const f32x4*)(fall + q * 256);
    float acc = 0.f;
    #pragma unroll 4
    for (int k = 0; k < 64; ++k) {
      f32x4 wv = w[k], fv = f[k];
      acc += wv.x * fv.x + wv.y * fv.y + wv.z * fv.z + wv.w * fv.w;
    }
    acc += __shfl_xor(acc, 1);
    acc += __shfl_xor(acc, 2);
    if (q == 0) out[o] = acc + bc[o];
  }
}

extern "C" void kernel_launch(void* const* d_in, const int* in_sizes, int n_in,
                              void* d_out, int out_size, void* d_ws, size_t ws_size,
                              hipStream_t stream) {
  // inputs: 0 feat(unused), 1 fa, 2 na, 3 W1a, 4 b1a, 5 fb, 6 nb, 7 W1b, 8 b1b,
  //         9 fc, 10 nc, 11 W1c, 12 b1c, 13 Wc, 14 bc
  const float* fa  = (const float*)d_in[1];
  const int*   na  = (const int*)d_in[2];
  const float* W1a = (const float*)d_in[3];
  const float* b1a = (const float*)d_in[4];
  const float* fb  = (const float*)d_in[5];
  const int*   nb  = (const int*)d_in[6];
  const float* W1b = (const float*)d_in[7];
  const float* b1b = (const float*)d_in[8];
  const float* fc  = (const float*)d_in[9];
  const int*   nc  = (const int*)d_in[10];
  const float* W1c = (const float*)d_in[11];
  const float* b1c = (const float*)d_in[12];
  const float* Wc  = (const float*)d_in[13];
  const float* bc  = (const float*)d_in[14];
  float* out = (float*)d_out;

  char*  wbf8 = (char*)d_ws + 4096;                                // 1.5 MB i8 fragments
  float* partials = (float*)((char*)d_ws + 4096 + 3 * 32 * 16 * 1024);        // 12.6 MB
  float* inter = partials + (size_t)NTILE * HID;                   // 768 KB

  k_convw<<<384, 256, 0, stream>>>(W1a, W1b, W1c, wbf8);
  k_main<<<NBLOCK, 256, 0, stream>>>(fa, fb, fc, na, nb, nc, b1a, b1b, b1c, wbf8, partials);
  k_reduce1<<<192, 256, 0, stream>>>(partials, inter);
  k_reduce2_final<<<1, 1024, 0, stream>>>(inter, Wc, bc, out);
}